// Round 9
// baseline (397.942 us; speedup 1.0000x reference)
//
#include <hip/hip_runtime.h>
#include <hip/hip_bf16.h>
#include <string.h>

#define N_FEAT 128
#define HIDDEN 64
#define N_CLS  40
#define SCAN_B 256
#define FILL_BLOCKS 1024
#define CHUNK_EDGES 2048

typedef __bf16 bf16x8 __attribute__((ext_vector_type(8)));
typedef float  f32x4  __attribute__((ext_vector_type(4)));

union Frag { unsigned u[4]; bf16x8 v; };

// physical XCD id of the CU running this wave [measured: learn_hip m09]
static __device__ inline int get_xcc() {
    return (int)(__builtin_amdgcn_s_getreg((3 << 11) | 20) & 7u);
}

// ---------------- bf16 pack/unpack (manual, RNE) ----------------

static __device__ inline unsigned pack_bf16(float a, float b) {
    unsigned ba = __float_as_uint(a);
    unsigned bb = __float_as_uint(b);
    unsigned ra = (ba + 0x7fffu + ((ba >> 16) & 1u)) >> 16;
    unsigned rb = (bb + 0x7fffu + ((bb >> 16) & 1u)) >> 16;
    return (ra & 0xffffu) | (rb << 16);
}

static __device__ inline float2 unpack_bf16(unsigned v) {
    return make_float2(__uint_as_float(v << 16), __uint_as_float(v & 0xffff0000u));
}

// ---------------- edge layout detection ----------------

__global__ void detect_layout_kernel(const int* __restrict__ ei, int* __restrict__ flag) {
    int lane = threadIdx.x;                 // one wave
    int v = ei[2 * lane + 1];
    unsigned long long b = __ballot(v != 0);
    if (lane == 0) flag[0] = (b == 0ull) ? 1 : 0;   // 1 => int64 layout
}

// ---------------- degree count: XCC-owned dst ranges, L2-local atomics ----------------
// Edge stream read with NON-TEMPORAL loads so it doesn't evict deg/cursor/csr
// lines from this XCD's L2 (the streams are never reused within an XCD).

__global__ __launch_bounds__(256) void count_kernel(const int* __restrict__ ei,
                                                    const int* __restrict__ flag,
                                                    unsigned* __restrict__ deg,
                                                    unsigned* __restrict__ ctr, int E, int N) {
    int r = get_xcc();
    int rng = (((N + 7) >> 3) + 15) & ~15;          // 64B-aligned range width
    int lo = r * rng;
    int hi = min(N, lo + rng);
    unsigned span = (unsigned)(hi - lo);
    bool is64 = (flag[0] != 0);
    const int* dstp = is64 ? (ei + 2 * E) : (ei + E);
    int stride = is64 ? 2 : 1;
    __shared__ unsigned chunk_s;
    for (;;) {
        if (threadIdx.x == 0)
            chunk_s = __hip_atomic_fetch_add(&ctr[r * 64], 1u, __ATOMIC_RELAXED,
                                             __HIP_MEMORY_SCOPE_WORKGROUP);
        __syncthreads();
        long long base = (long long)chunk_s * CHUNK_EDGES;
        __syncthreads();
        if (base >= E) break;
        int end = (int)min((long long)E, base + CHUNK_EDGES);
        for (int e = (int)base + threadIdx.x; e < end; e += 256) {
            int d = __builtin_nontemporal_load(dstp + (size_t)e * stride);
            if ((unsigned)(d - lo) < span)
                __hip_atomic_fetch_add(&deg[d], 1u, __ATOMIC_RELAXED,
                                       __HIP_MEMORY_SCOPE_WORKGROUP);
        }
    }
}

// ---------------- exclusive scan of deg -> rowptr (+ fused dinv) ----------------

__global__ void scan1_kernel(const unsigned* __restrict__ deg, unsigned* __restrict__ rowptr,
                             unsigned* __restrict__ blockSums, float* __restrict__ dinv, int N) {
    __shared__ unsigned tmp[SCAN_B];
    int i = blockIdx.x * SCAN_B + threadIdx.x;
    unsigned v = (i < N) ? deg[i] : 0u;
    if (i < N) dinv[i] = rsqrtf((float)(v + 1u));   // +1 self-loop
    tmp[threadIdx.x] = v;
    __syncthreads();
#pragma unroll
    for (int off = 1; off < SCAN_B; off <<= 1) {
        unsigned t = (threadIdx.x >= off) ? tmp[threadIdx.x - off] : 0u;
        __syncthreads();
        tmp[threadIdx.x] += t;
        __syncthreads();
    }
    if (i < N) rowptr[i] = tmp[threadIdx.x] - v;
    if (threadIdx.x == SCAN_B - 1) blockSums[blockIdx.x] = tmp[threadIdx.x];
}

__global__ void scan2_kernel(unsigned* __restrict__ blockSums, int nb) {
    __shared__ unsigned tmp[512];
    unsigned v = (threadIdx.x < (unsigned)nb) ? blockSums[threadIdx.x] : 0u;
    tmp[threadIdx.x] = v;
    __syncthreads();
#pragma unroll
    for (int off = 1; off < 512; off <<= 1) {
        unsigned t = (threadIdx.x >= (unsigned)off) ? tmp[threadIdx.x - off] : 0u;
        __syncthreads();
        tmp[threadIdx.x] += t;
        __syncthreads();
    }
    if (threadIdx.x < (unsigned)nb) blockSums[threadIdx.x] = tmp[threadIdx.x] - v;
}

__global__ void scan3_kernel(unsigned* __restrict__ rowptr, const unsigned* __restrict__ blockSums,
                             unsigned* __restrict__ cursor, int N) {
    int i = blockIdx.x * SCAN_B + threadIdx.x;
    if (i < N) {
        unsigned v = rowptr[i] + blockSums[blockIdx.x];
        rowptr[i] = v;
        cursor[i] = v;
    }
}

// ---------------- CSR fill: XCC-owned ranges, nt streams, L2-local atomics ----------------

__global__ __launch_bounds__(256) void csr_fill_kernel(const int* __restrict__ ei,
                                                       const int* __restrict__ flag,
                                                       unsigned* __restrict__ cursor,
                                                       unsigned* __restrict__ ctr,
                                                       int* __restrict__ csr_src, int E, int N) {
    int r = get_xcc();
    int rng = (((N + 7) >> 3) + 15) & ~15;
    int lo = r * rng;
    int hi = min(N, lo + rng);
    unsigned span = (unsigned)(hi - lo);
    bool is64 = (flag[0] != 0);
    const int* dstp = is64 ? (ei + 2 * E) : (ei + E);
    int stride = is64 ? 2 : 1;
    __shared__ unsigned chunk_s;
    for (;;) {
        if (threadIdx.x == 0)
            chunk_s = __hip_atomic_fetch_add(&ctr[r * 64], 1u, __ATOMIC_RELAXED,
                                             __HIP_MEMORY_SCOPE_WORKGROUP);
        __syncthreads();
        long long base = (long long)chunk_s * CHUNK_EDGES;
        __syncthreads();
        if (base >= E) break;
        int end = (int)min((long long)E, base + CHUNK_EDGES);
        for (int e = (int)base + threadIdx.x; e < end; e += 256) {
            int d = __builtin_nontemporal_load(dstp + (size_t)e * stride);
            if ((unsigned)(d - lo) < span) {
                int s = __builtin_nontemporal_load(ei + (size_t)e * stride);
                unsigned slot = __hip_atomic_fetch_add(&cursor[d], 1u, __ATOMIC_RELAXED,
                                                       __HIP_MEMORY_SCOPE_WORKGROUP);
                csr_src[slot] = s;
            }
        }
    }
}

// ---------------- GEMM1 (MFMA): x[N,128] f32 @ W1[128,64] f32 -> h1 bf16 [N,64] ----------------

__global__ __launch_bounds__(256) void gemm1_mfma_kernel(const float* __restrict__ x,
                                                         const float* __restrict__ W1,
                                                         unsigned* __restrict__ h1b, int N) {
    int lane = threadIdx.x & 63;
    int quad = lane >> 4;
    int col  = lane & 15;

    Frag B[4][4];
#pragma unroll
    for (int c = 0; c < 4; ++c)
#pragma unroll
        for (int ks = 0; ks < 4; ++ks) {
            int n = c * 16 + col;
#pragma unroll
            for (int jj = 0; jj < 4; ++jj) {
                int k = ks * 32 + quad * 8 + 2 * jj;
                B[c][ks].u[jj] = pack_bf16(W1[k * HIDDEN + n], W1[(k + 1) * HIDDEN + n]);
            }
        }

    int wave_id = blockIdx.x * 4 + (threadIdx.x >> 6);
    int nwaves  = gridDim.x * 4;
    int ntiles  = (N + 15) >> 4;

    for (int rt = wave_id; rt < ntiles; rt += nwaves) {
        int rowA = rt * 16 + col;
        Frag A[4];
#pragma unroll
        for (int ks = 0; ks < 4; ++ks) {
            float4 a0 = make_float4(0.f, 0.f, 0.f, 0.f), a1 = a0;
            if (rowA < N) {
                const float4* ap = (const float4*)(x + (size_t)rowA * N_FEAT + ks * 32 + quad * 8);
                a0 = ap[0];
                a1 = ap[1];
            }
            A[ks].u[0] = pack_bf16(a0.x, a0.y);
            A[ks].u[1] = pack_bf16(a0.z, a0.w);
            A[ks].u[2] = pack_bf16(a1.x, a1.y);
            A[ks].u[3] = pack_bf16(a1.z, a1.w);
        }
        f32x4 acc[4] = {{0.f, 0.f, 0.f, 0.f}, {0.f, 0.f, 0.f, 0.f},
                        {0.f, 0.f, 0.f, 0.f}, {0.f, 0.f, 0.f, 0.f}};
#pragma unroll
        for (int ks = 0; ks < 4; ++ks)
#pragma unroll
            for (int c = 0; c < 4; ++c)
                acc[c] = __builtin_amdgcn_mfma_f32_16x16x32_bf16(A[ks].v, B[c][ks].v, acc[c], 0, 0, 0);

        int rowD = rt * 16 + quad * 4;
#pragma unroll
        for (int c = 0; c < 4; ++c)
#pragma unroll
            for (int r = 0; r < 4; ++r) {
                float v = acc[c][r];
                float nxt = __shfl_down(v, 1);
                int row = rowD + r;
                if (((lane & 1) == 0) && row < N)
                    h1b[(size_t)row * 32 + ((c * 16 + col) >> 1)] = pack_bf16(v, nxt);
            }
    }
}

// ---------------- GEMM2 (MFMA): act bf16 [N,64] @ W2[64,40] f32 -> h2 bf16 [N,40] ----------------

__global__ __launch_bounds__(256) void gemm2_mfma_kernel(const unsigned* __restrict__ actb,
                                                         const float* __restrict__ W2,
                                                         unsigned* __restrict__ h2b, int N) {
    int lane = threadIdx.x & 63;
    int quad = lane >> 4;
    int col  = lane & 15;

    Frag B[3][2];
#pragma unroll
    for (int c = 0; c < 3; ++c)
#pragma unroll
        for (int ks = 0; ks < 2; ++ks) {
            int n = c * 16 + col;
#pragma unroll
            for (int jj = 0; jj < 4; ++jj) {
                int k = ks * 32 + quad * 8 + 2 * jj;
                float w0 = (n < N_CLS) ? W2[k * N_CLS + n] : 0.f;
                float w1 = (n < N_CLS) ? W2[(k + 1) * N_CLS + n] : 0.f;
                B[c][ks].u[jj] = pack_bf16(w0, w1);
            }
        }

    int wave_id = blockIdx.x * 4 + (threadIdx.x >> 6);
    int nwaves  = gridDim.x * 4;
    int ntiles  = (N + 15) >> 4;

    for (int rt = wave_id; rt < ntiles; rt += nwaves) {
        int rowA = rt * 16 + col;
        Frag A[2];
#pragma unroll
        for (int ks = 0; ks < 2; ++ks) {
            uint4 u = make_uint4(0u, 0u, 0u, 0u);
            if (rowA < N)
                u = *(const uint4*)(actb + (size_t)rowA * 32 + ks * 16 + quad * 4);
            A[ks].u[0] = u.x; A[ks].u[1] = u.y; A[ks].u[2] = u.z; A[ks].u[3] = u.w;
        }
        f32x4 acc[3] = {{0.f, 0.f, 0.f, 0.f}, {0.f, 0.f, 0.f, 0.f}, {0.f, 0.f, 0.f, 0.f}};
#pragma unroll
        for (int ks = 0; ks < 2; ++ks)
#pragma unroll
            for (int c = 0; c < 3; ++c)
                acc[c] = __builtin_amdgcn_mfma_f32_16x16x32_bf16(A[ks].v, B[c][ks].v, acc[c], 0, 0, 0);

        int rowD = rt * 16 + quad * 4;
#pragma unroll
        for (int c = 0; c < 3; ++c)
#pragma unroll
            for (int r = 0; r < 4; ++r) {
                float v = acc[c][r];
                float nxt = __shfl_down(v, 1);
                int row = rowD + r;
                int pair = (c * 16 + col) >> 1;
                if (((lane & 1) == 0) && pair < 20 && row < N)
                    h2b[(size_t)row * 20 + pair] = pack_bf16(v, nxt);
            }
    }
}

// ---------------- layer-1 agg: 8-edge unrolled CSR gather + self + bias + ReLU ----------------

__global__ __launch_bounds__(256) void agg1_kernel(const unsigned* __restrict__ h1b,
                                                   const int* __restrict__ csr_src,
                                                   const unsigned* __restrict__ rowptr,
                                                   const unsigned* __restrict__ deg,
                                                   const float* __restrict__ dinv,
                                                   const float* __restrict__ b1,
                                                   unsigned* __restrict__ actb, int N) {
    int wave = threadIdx.x >> 6, lane = threadIdx.x & 63;
    int sub = lane >> 5, j = lane & 31;
    int d = blockIdx.x * 4 + wave;
    if (d >= N) return;
    float dv = dinv[d];
    float acc0 = 0.f, acc1 = 0.f;
    if (sub == 0) {
        float2 v = unpack_bf16(h1b[(size_t)d * 32 + j]);
        acc0 = dv * v.x; acc1 = dv * v.y;
    }
    unsigned beg = rowptr[d];
    int len = (int)deg[d];
    int i = 0;
    for (; i + 8 <= len; i += 8) {
        int s0 = csr_src[beg + i + sub];
        int s1 = csr_src[beg + i + 2 + sub];
        int s2 = csr_src[beg + i + 4 + sub];
        int s3 = csr_src[beg + i + 6 + sub];
        float w0 = dinv[s0], w1 = dinv[s1], w2 = dinv[s2], w3 = dinv[s3];
        unsigned v0 = h1b[(size_t)s0 * 32 + j];
        unsigned v1 = h1b[(size_t)s1 * 32 + j];
        unsigned v2 = h1b[(size_t)s2 * 32 + j];
        unsigned v3 = h1b[(size_t)s3 * 32 + j];
        float2 a0 = unpack_bf16(v0), a1 = unpack_bf16(v1);
        float2 a2 = unpack_bf16(v2), a3 = unpack_bf16(v3);
        acc0 += w0 * a0.x + w1 * a1.x + w2 * a2.x + w3 * a3.x;
        acc1 += w0 * a0.y + w1 * a1.y + w2 * a2.y + w3 * a3.y;
    }
    for (; i + 4 <= len; i += 4) {
        int sA = csr_src[beg + i + sub];
        int sB = csr_src[beg + i + 2 + sub];
        float wA = dinv[sA], wB = dinv[sB];
        float2 a = unpack_bf16(h1b[(size_t)sA * 32 + j]);
        float2 b = unpack_bf16(h1b[(size_t)sB * 32 + j]);
        acc0 += wA * a.x + wB * b.x;
        acc1 += wA * a.y + wB * b.y;
    }
    for (; i < len; i += 2) {
        int e = i + sub;
        if (e < len) {
            int s = csr_src[beg + e];
            float w = dinv[s];
            float2 a = unpack_bf16(h1b[(size_t)s * 32 + j]);
            acc0 += w * a.x;
            acc1 += w * a.y;
        }
    }
    acc0 += __shfl_xor(acc0, 32);
    acc1 += __shfl_xor(acc1, 32);
    if (sub == 0) {
        float2 bb = ((const float2*)b1)[j];
        float r0 = fmaxf(acc0 * dv + bb.x, 0.f);
        float r1 = fmaxf(acc1 * dv + bb.y, 0.f);
        actb[(size_t)d * 32 + j] = pack_bf16(r0, r1);
    }
}

// ---------------- layer-2 agg: 8-edge unrolled gather + bias + log_softmax ----------------

__global__ __launch_bounds__(256) void agg2_lsm_kernel(const unsigned* __restrict__ h2b,
                                                       const int* __restrict__ csr_src,
                                                       const unsigned* __restrict__ rowptr,
                                                       const unsigned* __restrict__ deg,
                                                       const float* __restrict__ dinv,
                                                       const float* __restrict__ b2,
                                                       float* __restrict__ out, int N) {
    int wave = threadIdx.x >> 6, lane = threadIdx.x & 63;
    int sub = lane >> 5, j = lane & 31;
    bool act = (j < 20);
    int d = blockIdx.x * 4 + wave;
    if (d >= N) return;
    float dv = dinv[d];
    float acc0 = 0.f, acc1 = 0.f;
    if (sub == 0 && act) {
        float2 v = unpack_bf16(h2b[(size_t)d * 20 + j]);
        acc0 = dv * v.x; acc1 = dv * v.y;
    }
    unsigned beg = rowptr[d];
    int len = (int)deg[d];
    int i = 0;
    for (; i + 8 <= len; i += 8) {
        int s0 = csr_src[beg + i + sub];
        int s1 = csr_src[beg + i + 2 + sub];
        int s2 = csr_src[beg + i + 4 + sub];
        int s3 = csr_src[beg + i + 6 + sub];
        float w0 = dinv[s0], w1 = dinv[s1], w2 = dinv[s2], w3 = dinv[s3];
        if (act) {
            float2 a0 = unpack_bf16(h2b[(size_t)s0 * 20 + j]);
            float2 a1 = unpack_bf16(h2b[(size_t)s1 * 20 + j]);
            float2 a2 = unpack_bf16(h2b[(size_t)s2 * 20 + j]);
            float2 a3 = unpack_bf16(h2b[(size_t)s3 * 20 + j]);
            acc0 += w0 * a0.x + w1 * a1.x + w2 * a2.x + w3 * a3.x;
            acc1 += w0 * a0.y + w1 * a1.y + w2 * a2.y + w3 * a3.y;
        }
    }
    for (; i + 4 <= len; i += 4) {
        int sA = csr_src[beg + i + sub];
        int sB = csr_src[beg + i + 2 + sub];
        float wA = dinv[sA], wB = dinv[sB];
        if (act) {
            float2 a = unpack_bf16(h2b[(size_t)sA * 20 + j]);
            float2 b = unpack_bf16(h2b[(size_t)sB * 20 + j]);
            acc0 += wA * a.x + wB * b.x;
            acc1 += wA * a.y + wB * b.y;
        }
    }
    for (; i < len; i += 2) {
        int e = i + sub;
        if (e < len && act) {
            int s = csr_src[beg + e];
            float w = dinv[s];
            float2 a = unpack_bf16(h2b[(size_t)s * 20 + j]);
            acc0 += w * a.x;
            acc1 += w * a.y;
        }
    }
    acc0 += __shfl_xor(acc0, 32);
    acc1 += __shfl_xor(acc1, 32);
    float v0 = -1e30f, v1 = -1e30f;
    if (act) {
        float2 bb = ((const float2*)b2)[j];
        v0 = acc0 * dv + bb.x;
        v1 = acc1 * dv + bb.y;
    }
    float m = fmaxf(v0, v1);
#pragma unroll
    for (int off = 32; off > 0; off >>= 1)
        m = fmaxf(m, __shfl_xor(m, off));
    float ex = (act && sub == 0) ? (expf(v0 - m) + expf(v1 - m)) : 0.f;
#pragma unroll
    for (int off = 32; off > 0; off >>= 1)
        ex += __shfl_xor(ex, off);
    float ls = logf(ex);
    if (act && sub == 0) {
        float2* orow = (float2*)(out + (size_t)d * N_CLS);
        orow[j] = make_float2(v0 - m - ls, v1 - m - ls);
    }
}

// ---------------- launch ----------------

static inline size_t align_up(size_t x) { return (x + 255) & ~(size_t)255; }

extern "C" void kernel_launch(void* const* d_in, const int* in_sizes, int n_in,
                              void* d_out, int out_size, void* d_ws, size_t ws_size,
                              hipStream_t stream) {
    const float* x  = (const float*)d_in[0];
    const int*   ei = (const int*)d_in[1];
    const float* W1 = (const float*)d_in[2];
    const float* b1 = (const float*)d_in[3];
    const float* W2 = (const float*)d_in[4];
    const float* b2 = (const float*)d_in[5];

    int N = in_sizes[0] / N_FEAT;     // 100000
    int E = in_sizes[1] / 2;          // 1600000
    int nb = (N + SCAN_B - 1) / SCAN_B;

    char* ws = (char*)d_ws;
    int*      flag    = (int*)ws;       ws += 256;
    unsigned* ctrs    = (unsigned*)ws;  ws += 4096;   // 2 sets x 8 XCD counters, 256B apart
    unsigned* deg     = (unsigned*)ws;  ws += align_up((size_t)N * 4);
    float*    dinv    = (float*)ws;     ws += align_up((size_t)N * 4);
    unsigned* rowptr  = (unsigned*)ws;  ws += align_up((size_t)N * 4);
    unsigned* cursor  = (unsigned*)ws;  ws += align_up((size_t)N * 4);
    unsigned* bsums   = (unsigned*)ws;  ws += align_up((size_t)nb * 4);
    int*      csr_src = (int*)ws;       ws += align_up((size_t)E * 4);
    unsigned* h1b     = (unsigned*)ws;  ws += align_up((size_t)N * 32 * 4);   // bf16 [N,64]
    unsigned* actb    = (unsigned*)ws;  ws += align_up((size_t)N * 32 * 4);   // bf16 [N,64]
    unsigned* h2b     = (unsigned*)ws;  ws += align_up((size_t)N * 20 * 4);   // bf16 [N,40]

    hipMemsetAsync(ctrs, 0, 4096, stream);
    hipMemsetAsync(deg, 0, (size_t)N * 4, stream);

    detect_layout_kernel<<<1, 64, 0, stream>>>(ei, flag);
    count_kernel<<<FILL_BLOCKS, 256, 0, stream>>>(ei, flag, deg, ctrs, E, N);

    scan1_kernel<<<nb, SCAN_B, 0, stream>>>(deg, rowptr, bsums, dinv, N);
    scan2_kernel<<<1, 512, 0, stream>>>(bsums, nb);
    scan3_kernel<<<nb, SCAN_B, 0, stream>>>(rowptr, bsums, cursor, N);
    csr_fill_kernel<<<FILL_BLOCKS, 256, 0, stream>>>(ei, flag, cursor, ctrs + 512, csr_src, E, N);

    // layer 1
    gemm1_mfma_kernel<<<512, 256, 0, stream>>>(x, W1, h1b, N);
    agg1_kernel<<<(N + 3) / 4, 256, 0, stream>>>(h1b, csr_src, rowptr, deg, dinv, b1, actb, N);

    // layer 2
    gemm2_mfma_kernel<<<512, 256, 0, stream>>>(actb, W2, h2b, N);
    agg2_lsm_kernel<<<(N + 3) / 4, 256, 0, stream>>>(h2b, csr_src, rowptr, deg, dinv, b2, (float*)d_out, N);
}

// Round 10
// 352.584 us; speedup vs baseline: 1.1286x; 1.1286x over previous
//
#include <hip/hip_runtime.h>
#include <hip/hip_bf16.h>
#include <string.h>

#define N_FEAT 128
#define HIDDEN 64
#define N_CLS  40
#define FILL_BLOCKS 1024
#define CHUNK_EDGES 1024
#define B_BITS 6                 // 64 dsts per bucket
#define SRC_BITS 17              // N <= 131072

typedef __bf16 bf16x8 __attribute__((ext_vector_type(8)));
typedef float  f32x4  __attribute__((ext_vector_type(4)));

union Frag { unsigned u[4]; bf16x8 v; };

// physical XCD id of the CU running this wave [measured: learn_hip m09]
static __device__ inline int get_xcc() {
    return (int)(__builtin_amdgcn_s_getreg((3 << 11) | 20) & 7u);
}

// ---------------- bf16 pack/unpack (manual, RNE) ----------------

static __device__ inline unsigned pack_bf16(float a, float b) {
    unsigned ba = __float_as_uint(a);
    unsigned bb = __float_as_uint(b);
    unsigned ra = (ba + 0x7fffu + ((ba >> 16) & 1u)) >> 16;
    unsigned rb = (bb + 0x7fffu + ((bb >> 16) & 1u)) >> 16;
    return (ra & 0xffffu) | (rb << 16);
}

static __device__ inline float2 unpack_bf16(unsigned v) {
    return make_float2(__uint_as_float(v << 16), __uint_as_float(v & 0xffff0000u));
}

// ---------------- edge layout detection ----------------

__global__ void detect_layout_kernel(const int* __restrict__ ei, int* __restrict__ flag) {
    int lane = threadIdx.x;                 // one wave
    int v = ei[2 * lane + 1];
    unsigned long long b = __ballot(v != 0);
    if (lane == 0) flag[0] = (b == 0ull) ? 1 : 0;   // 1 => int64 layout
}

// ---------------- bucket histogram: LDS hist per block, one flush ----------------

__global__ __launch_bounds__(256) void bucket_hist_kernel(const int* __restrict__ ei,
                                                          const int* __restrict__ flag,
                                                          unsigned* __restrict__ bcnt,
                                                          int E, int nbuk) {
    __shared__ unsigned h[2048];
    for (int i = threadIdx.x; i < nbuk; i += 256) h[i] = 0u;
    __syncthreads();
    bool is64 = (flag[0] != 0);
    const int* dstp = is64 ? (ei + 2 * E) : (ei + E);
    int stride = is64 ? 2 : 1;
    for (int e = blockIdx.x * 256 + threadIdx.x; e < E; e += gridDim.x * 256) {
        int d = dstp[(size_t)e * stride];
        atomicAdd(&h[d >> B_BITS], 1u);
    }
    __syncthreads();
    for (int i = threadIdx.x; i < nbuk; i += 256)
        if (h[i]) atomicAdd(&bcnt[i], h[i]);
}

// ---------------- bucket scan: exclusive scan of bcnt -> bbase, init bcur ----------------
// single block, 512 threads, loops over nbuk (<= 2048) in 512-wide rounds.

__global__ __launch_bounds__(512) void bucket_scan_kernel(const unsigned* __restrict__ bcnt,
                                                          unsigned* __restrict__ bbase,
                                                          unsigned* __restrict__ bcur, int nbuk) {
    __shared__ unsigned tmp[512];
    __shared__ unsigned carry;
    if (threadIdx.x == 0) carry = 0u;
    __syncthreads();
    for (int base = 0; base < nbuk; base += 512) {
        int i = base + threadIdx.x;
        unsigned v = (i < nbuk) ? bcnt[i] : 0u;
        tmp[threadIdx.x] = v;
        __syncthreads();
#pragma unroll
        for (int off = 1; off < 512; off <<= 1) {
            unsigned t = (threadIdx.x >= (unsigned)off) ? tmp[threadIdx.x - off] : 0u;
            __syncthreads();
            tmp[threadIdx.x] += t;
            __syncthreads();
        }
        unsigned excl = tmp[threadIdx.x] - v + carry;
        if (i < nbuk) {
            bbase[i] = excl;
            bcur[(size_t)i * 16] = excl;   // line-strided cursor (one 64B line per bucket)
        }
        __syncthreads();
        if (threadIdx.x == 511) carry += tmp[511];
        __syncthreads();
    }
}

// ---------------- fill buckets: XCC-owned bucket ranges, L2-local cursors ----------------
// tmp entry = src | (dlocal << SRC_BITS). Write-front = one line per bucket
// (196 lines/XCD ~ 12.5 KB) so lines fully assemble in the owning L2.

__global__ __launch_bounds__(256) void fill_buckets_kernel(const int* __restrict__ ei,
                                                           const int* __restrict__ flag,
                                                           unsigned* __restrict__ bcur,
                                                           unsigned* __restrict__ ctr,
                                                           unsigned* __restrict__ tmpbuf,
                                                           int E, int nbuk) {
    int r = get_xcc();
    int bpx = (nbuk + 7) >> 3;
    int blo = r * bpx;
    int bhi = min(nbuk, blo + bpx);
    bool is64 = (flag[0] != 0);
    const int* dstp = is64 ? (ei + 2 * E) : (ei + E);
    int stride = is64 ? 2 : 1;
    __shared__ unsigned chunk_s;
    for (;;) {
        if (threadIdx.x == 0)
            chunk_s = __hip_atomic_fetch_add(&ctr[r * 64], 1u, __ATOMIC_RELAXED,
                                             __HIP_MEMORY_SCOPE_WORKGROUP);
        __syncthreads();
        long long base = (long long)chunk_s * CHUNK_EDGES;
        __syncthreads();
        if (base >= E) break;
        int end = (int)min((long long)E, base + CHUNK_EDGES);
        for (int e = (int)base + threadIdx.x; e < end; e += 256) {
            int d = dstp[(size_t)e * stride];
            int b = d >> B_BITS;
            if (b >= blo && b < bhi) {
                int s = ei[(size_t)e * stride];
                unsigned val = (unsigned)s | ((unsigned)(d & ((1 << B_BITS) - 1)) << SRC_BITS);
                unsigned slot = __hip_atomic_fetch_add(&bcur[(size_t)b * 16], 1u, __ATOMIC_RELAXED,
                                                       __HIP_MEMORY_SCOPE_WORKGROUP);
                tmpbuf[slot] = val;
            }
        }
    }
}

// ---------------- stage2: bucket -> exact CSR + deg + rowptr + dinv ----------------
// one block per bucket; zero global atomics.

__global__ __launch_bounds__(256) void bucket_to_csr_kernel(const unsigned* __restrict__ tmpbuf,
                                                            const unsigned* __restrict__ bbase,
                                                            unsigned* __restrict__ deg,
                                                            unsigned* __restrict__ rowptr,
                                                            float* __restrict__ dinv,
                                                            int* __restrict__ csr_src,
                                                            int nbuk, int N, int E) {
    int b = blockIdx.x;
    int tid = threadIdx.x;
    unsigned beg = bbase[b];
    unsigned end = (b + 1 < nbuk) ? bbase[b + 1] : (unsigned)E;
    int d0 = b << B_BITS;
    const int ND = 1 << B_BITS;
    __shared__ unsigned hist[ND], scn[ND], cur[ND];
    if (tid < ND) { hist[tid] = 0u; cur[tid] = 0u; }
    __syncthreads();
    for (unsigned i = beg + tid; i < end; i += 256)
        atomicAdd(&hist[tmpbuf[i] >> SRC_BITS], 1u);
    __syncthreads();
    if (tid == 0) {
        unsigned run = 0;
        for (int k = 0; k < ND; ++k) { scn[k] = run; run += hist[k]; }
    }
    __syncthreads();
    if (tid < ND) {
        int d = d0 + tid;
        if (d < N) {
            unsigned dg = hist[tid];
            deg[d] = dg;
            dinv[d] = rsqrtf((float)(dg + 1u));
            rowptr[d] = beg + scn[tid];
        }
    }
    __syncthreads();
    for (unsigned i = beg + tid; i < end; i += 256) {
        unsigned v = tmpbuf[i];
        unsigned dl = v >> SRC_BITS;
        unsigned s = v & ((1u << SRC_BITS) - 1u);
        unsigned p = atomicAdd(&cur[dl], 1u);
        csr_src[beg + scn[dl] + p] = (int)s;
    }
}

// ---------------- GEMM1 (MFMA): x[N,128] f32 @ W1[128,64] f32 -> h1 bf16 [N,64] ----------------

__global__ __launch_bounds__(256) void gemm1_mfma_kernel(const float* __restrict__ x,
                                                         const float* __restrict__ W1,
                                                         unsigned* __restrict__ h1b, int N) {
    int lane = threadIdx.x & 63;
    int quad = lane >> 4;
    int col  = lane & 15;

    Frag B[4][4];
#pragma unroll
    for (int c = 0; c < 4; ++c)
#pragma unroll
        for (int ks = 0; ks < 4; ++ks) {
            int n = c * 16 + col;
#pragma unroll
            for (int jj = 0; jj < 4; ++jj) {
                int k = ks * 32 + quad * 8 + 2 * jj;
                B[c][ks].u[jj] = pack_bf16(W1[k * HIDDEN + n], W1[(k + 1) * HIDDEN + n]);
            }
        }

    int wave_id = blockIdx.x * 4 + (threadIdx.x >> 6);
    int nwaves  = gridDim.x * 4;
    int ntiles  = (N + 15) >> 4;

    for (int rt = wave_id; rt < ntiles; rt += nwaves) {
        int rowA = rt * 16 + col;
        Frag A[4];
#pragma unroll
        for (int ks = 0; ks < 4; ++ks) {
            float4 a0 = make_float4(0.f, 0.f, 0.f, 0.f), a1 = a0;
            if (rowA < N) {
                const float4* ap = (const float4*)(x + (size_t)rowA * N_FEAT + ks * 32 + quad * 8);
                a0 = ap[0];
                a1 = ap[1];
            }
            A[ks].u[0] = pack_bf16(a0.x, a0.y);
            A[ks].u[1] = pack_bf16(a0.z, a0.w);
            A[ks].u[2] = pack_bf16(a1.x, a1.y);
            A[ks].u[3] = pack_bf16(a1.z, a1.w);
        }
        f32x4 acc[4] = {{0.f, 0.f, 0.f, 0.f}, {0.f, 0.f, 0.f, 0.f},
                        {0.f, 0.f, 0.f, 0.f}, {0.f, 0.f, 0.f, 0.f}};
#pragma unroll
        for (int ks = 0; ks < 4; ++ks)
#pragma unroll
            for (int c = 0; c < 4; ++c)
                acc[c] = __builtin_amdgcn_mfma_f32_16x16x32_bf16(A[ks].v, B[c][ks].v, acc[c], 0, 0, 0);

        int rowD = rt * 16 + quad * 4;
#pragma unroll
        for (int c = 0; c < 4; ++c)
#pragma unroll
            for (int r = 0; r < 4; ++r) {
                float v = acc[c][r];
                float nxt = __shfl_down(v, 1);
                int row = rowD + r;
                if (((lane & 1) == 0) && row < N)
                    h1b[(size_t)row * 32 + ((c * 16 + col) >> 1)] = pack_bf16(v, nxt);
            }
    }
}

// ---------------- GEMM2 (MFMA): act bf16 [N,64] @ W2[64,40] f32 -> h2 bf16 [N,40] ----------------

__global__ __launch_bounds__(256) void gemm2_mfma_kernel(const unsigned* __restrict__ actb,
                                                         const float* __restrict__ W2,
                                                         unsigned* __restrict__ h2b, int N) {
    int lane = threadIdx.x & 63;
    int quad = lane >> 4;
    int col  = lane & 15;

    Frag B[3][2];
#pragma unroll
    for (int c = 0; c < 3; ++c)
#pragma unroll
        for (int ks = 0; ks < 2; ++ks) {
            int n = c * 16 + col;
#pragma unroll
            for (int jj = 0; jj < 4; ++jj) {
                int k = ks * 32 + quad * 8 + 2 * jj;
                float w0 = (n < N_CLS) ? W2[k * N_CLS + n] : 0.f;
                float w1 = (n < N_CLS) ? W2[(k + 1) * N_CLS + n] : 0.f;
                B[c][ks].u[jj] = pack_bf16(w0, w1);
            }
        }

    int wave_id = blockIdx.x * 4 + (threadIdx.x >> 6);
    int nwaves  = gridDim.x * 4;
    int ntiles  = (N + 15) >> 4;

    for (int rt = wave_id; rt < ntiles; rt += nwaves) {
        int rowA = rt * 16 + col;
        Frag A[2];
#pragma unroll
        for (int ks = 0; ks < 2; ++ks) {
            uint4 u = make_uint4(0u, 0u, 0u, 0u);
            if (rowA < N)
                u = *(const uint4*)(actb + (size_t)rowA * 32 + ks * 16 + quad * 4);
            A[ks].u[0] = u.x; A[ks].u[1] = u.y; A[ks].u[2] = u.z; A[ks].u[3] = u.w;
        }
        f32x4 acc[3] = {{0.f, 0.f, 0.f, 0.f}, {0.f, 0.f, 0.f, 0.f}, {0.f, 0.f, 0.f, 0.f}};
#pragma unroll
        for (int ks = 0; ks < 2; ++ks)
#pragma unroll
            for (int c = 0; c < 3; ++c)
                acc[c] = __builtin_amdgcn_mfma_f32_16x16x32_bf16(A[ks].v, B[c][ks].v, acc[c], 0, 0, 0);

        int rowD = rt * 16 + quad * 4;
#pragma unroll
        for (int c = 0; c < 3; ++c)
#pragma unroll
            for (int r = 0; r < 4; ++r) {
                float v = acc[c][r];
                float nxt = __shfl_down(v, 1);
                int row = rowD + r;
                int pair = (c * 16 + col) >> 1;
                if (((lane & 1) == 0) && pair < 20 && row < N)
                    h2b[(size_t)row * 20 + pair] = pack_bf16(v, nxt);
            }
    }
}

// ---------------- layer-1 agg: 8-edge unrolled CSR gather + self + bias + ReLU ----------------

__global__ __launch_bounds__(256) void agg1_kernel(const unsigned* __restrict__ h1b,
                                                   const int* __restrict__ csr_src,
                                                   const unsigned* __restrict__ rowptr,
                                                   const unsigned* __restrict__ deg,
                                                   const float* __restrict__ dinv,
                                                   const float* __restrict__ b1,
                                                   unsigned* __restrict__ actb, int N) {
    int wave = threadIdx.x >> 6, lane = threadIdx.x & 63;
    int sub = lane >> 5, j = lane & 31;
    int d = blockIdx.x * 4 + wave;
    if (d >= N) return;
    float dv = dinv[d];
    float acc0 = 0.f, acc1 = 0.f;
    if (sub == 0) {
        float2 v = unpack_bf16(h1b[(size_t)d * 32 + j]);
        acc0 = dv * v.x; acc1 = dv * v.y;
    }
    unsigned beg = rowptr[d];
    int len = (int)deg[d];
    int i = 0;
    for (; i + 8 <= len; i += 8) {
        int s0 = csr_src[beg + i + sub];
        int s1 = csr_src[beg + i + 2 + sub];
        int s2 = csr_src[beg + i + 4 + sub];
        int s3 = csr_src[beg + i + 6 + sub];
        float w0 = dinv[s0], w1 = dinv[s1], w2 = dinv[s2], w3 = dinv[s3];
        unsigned v0 = h1b[(size_t)s0 * 32 + j];
        unsigned v1 = h1b[(size_t)s1 * 32 + j];
        unsigned v2 = h1b[(size_t)s2 * 32 + j];
        unsigned v3 = h1b[(size_t)s3 * 32 + j];
        float2 a0 = unpack_bf16(v0), a1 = unpack_bf16(v1);
        float2 a2 = unpack_bf16(v2), a3 = unpack_bf16(v3);
        acc0 += w0 * a0.x + w1 * a1.x + w2 * a2.x + w3 * a3.x;
        acc1 += w0 * a0.y + w1 * a1.y + w2 * a2.y + w3 * a3.y;
    }
    for (; i + 4 <= len; i += 4) {
        int sA = csr_src[beg + i + sub];
        int sB = csr_src[beg + i + 2 + sub];
        float wA = dinv[sA], wB = dinv[sB];
        float2 a = unpack_bf16(h1b[(size_t)sA * 32 + j]);
        float2 b = unpack_bf16(h1b[(size_t)sB * 32 + j]);
        acc0 += wA * a.x + wB * b.x;
        acc1 += wA * a.y + wB * b.y;
    }
    for (; i < len; i += 2) {
        int e = i + sub;
        if (e < len) {
            int s = csr_src[beg + e];
            float w = dinv[s];
            float2 a = unpack_bf16(h1b[(size_t)s * 32 + j]);
            acc0 += w * a.x;
            acc1 += w * a.y;
        }
    }
    acc0 += __shfl_xor(acc0, 32);
    acc1 += __shfl_xor(acc1, 32);
    if (sub == 0) {
        float2 bb = ((const float2*)b1)[j];
        float r0 = fmaxf(acc0 * dv + bb.x, 0.f);
        float r1 = fmaxf(acc1 * dv + bb.y, 0.f);
        actb[(size_t)d * 32 + j] = pack_bf16(r0, r1);
    }
}

// ---------------- layer-2 agg: 8-edge unrolled gather + bias + log_softmax ----------------

__global__ __launch_bounds__(256) void agg2_lsm_kernel(const unsigned* __restrict__ h2b,
                                                       const int* __restrict__ csr_src,
                                                       const unsigned* __restrict__ rowptr,
                                                       const unsigned* __restrict__ deg,
                                                       const float* __restrict__ dinv,
                                                       const float* __restrict__ b2,
                                                       float* __restrict__ out, int N) {
    int wave = threadIdx.x >> 6, lane = threadIdx.x & 63;
    int sub = lane >> 5, j = lane & 31;
    bool act = (j < 20);
    int d = blockIdx.x * 4 + wave;
    if (d >= N) return;
    float dv = dinv[d];
    float acc0 = 0.f, acc1 = 0.f;
    if (sub == 0 && act) {
        float2 v = unpack_bf16(h2b[(size_t)d * 20 + j]);
        acc0 = dv * v.x; acc1 = dv * v.y;
    }
    unsigned beg = rowptr[d];
    int len = (int)deg[d];
    int i = 0;
    for (; i + 8 <= len; i += 8) {
        int s0 = csr_src[beg + i + sub];
        int s1 = csr_src[beg + i + 2 + sub];
        int s2 = csr_src[beg + i + 4 + sub];
        int s3 = csr_src[beg + i + 6 + sub];
        float w0 = dinv[s0], w1 = dinv[s1], w2 = dinv[s2], w3 = dinv[s3];
        if (act) {
            float2 a0 = unpack_bf16(h2b[(size_t)s0 * 20 + j]);
            float2 a1 = unpack_bf16(h2b[(size_t)s1 * 20 + j]);
            float2 a2 = unpack_bf16(h2b[(size_t)s2 * 20 + j]);
            float2 a3 = unpack_bf16(h2b[(size_t)s3 * 20 + j]);
            acc0 += w0 * a0.x + w1 * a1.x + w2 * a2.x + w3 * a3.x;
            acc1 += w0 * a0.y + w1 * a1.y + w2 * a2.y + w3 * a3.y;
        }
    }
    for (; i + 4 <= len; i += 4) {
        int sA = csr_src[beg + i + sub];
        int sB = csr_src[beg + i + 2 + sub];
        float wA = dinv[sA], wB = dinv[sB];
        if (act) {
            float2 a = unpack_bf16(h2b[(size_t)sA * 20 + j]);
            float2 b = unpack_bf16(h2b[(size_t)sB * 20 + j]);
            acc0 += wA * a.x + wB * b.x;
            acc1 += wA * a.y + wB * b.y;
        }
    }
    for (; i < len; i += 2) {
        int e = i + sub;
        if (e < len && act) {
            int s = csr_src[beg + e];
            float w = dinv[s];
            float2 a = unpack_bf16(h2b[(size_t)s * 20 + j]);
            acc0 += w * a.x;
            acc1 += w * a.y;
        }
    }
    acc0 += __shfl_xor(acc0, 32);
    acc1 += __shfl_xor(acc1, 32);
    float v0 = -1e30f, v1 = -1e30f;
    if (act) {
        float2 bb = ((const float2*)b2)[j];
        v0 = acc0 * dv + bb.x;
        v1 = acc1 * dv + bb.y;
    }
    float m = fmaxf(v0, v1);
#pragma unroll
    for (int off = 32; off > 0; off >>= 1)
        m = fmaxf(m, __shfl_xor(m, off));
    float ex = (act && sub == 0) ? (expf(v0 - m) + expf(v1 - m)) : 0.f;
#pragma unroll
    for (int off = 32; off > 0; off >>= 1)
        ex += __shfl_xor(ex, off);
    float ls = logf(ex);
    if (act && sub == 0) {
        float2* orow = (float2*)(out + (size_t)d * N_CLS);
        orow[j] = make_float2(v0 - m - ls, v1 - m - ls);
    }
}

// ---------------- launch ----------------

static inline size_t align_up(size_t x) { return (x + 255) & ~(size_t)255; }

extern "C" void kernel_launch(void* const* d_in, const int* in_sizes, int n_in,
                              void* d_out, int out_size, void* d_ws, size_t ws_size,
                              hipStream_t stream) {
    const float* x  = (const float*)d_in[0];
    const int*   ei = (const int*)d_in[1];
    const float* W1 = (const float*)d_in[2];
    const float* b1 = (const float*)d_in[3];
    const float* W2 = (const float*)d_in[4];
    const float* b2 = (const float*)d_in[5];

    int N = in_sizes[0] / N_FEAT;     // 100000
    int E = in_sizes[1] / 2;          // 1600000
    int nbuk = (N + (1 << B_BITS) - 1) >> B_BITS;   // 1563

    char* ws = (char*)d_ws;
    int*      flag    = (int*)ws;       ws += 256;
    unsigned* ctrs    = (unsigned*)ws;  ws += 4096;                        // 8 XCD chunk counters, 256B apart
    unsigned* bcnt    = (unsigned*)ws;  ws += align_up((size_t)nbuk * 4);
    unsigned* bbase   = (unsigned*)ws;  ws += align_up((size_t)nbuk * 4);
    unsigned* bcur    = (unsigned*)ws;  ws += align_up((size_t)nbuk * 64); // line-strided cursors
    unsigned* deg     = (unsigned*)ws;  ws += align_up((size_t)N * 4);
    float*    dinv    = (float*)ws;     ws += align_up((size_t)N * 4);
    unsigned* rowptr  = (unsigned*)ws;  ws += align_up((size_t)N * 4);
    unsigned* tmpbuf  = (unsigned*)ws;  ws += align_up((size_t)E * 4);
    int*      csr_src = (int*)ws;       ws += align_up((size_t)E * 4);
    unsigned* h1b     = (unsigned*)ws;  ws += align_up((size_t)N * 32 * 4);   // bf16 [N,64]
    unsigned* actb    = (unsigned*)ws;  ws += align_up((size_t)N * 32 * 4);   // bf16 [N,64]
    unsigned* h2b     = (unsigned*)ws;  ws += align_up((size_t)N * 20 * 4);   // bf16 [N,40]

    hipMemsetAsync(ctrs, 0, 4096, stream);
    hipMemsetAsync(bcnt, 0, (size_t)nbuk * 4, stream);

    detect_layout_kernel<<<1, 64, 0, stream>>>(ei, flag);
    bucket_hist_kernel<<<256, 256, 0, stream>>>(ei, flag, bcnt, E, nbuk);
    bucket_scan_kernel<<<1, 512, 0, stream>>>(bcnt, bbase, bcur, nbuk);
    fill_buckets_kernel<<<FILL_BLOCKS, 256, 0, stream>>>(ei, flag, bcur, ctrs, tmpbuf, E, nbuk);
    bucket_to_csr_kernel<<<nbuk, 256, 0, stream>>>(tmpbuf, bbase, deg, rowptr, dinv, csr_src, nbuk, N, E);

    // layer 1
    gemm1_mfma_kernel<<<512, 256, 0, stream>>>(x, W1, h1b, N);
    agg1_kernel<<<(N + 3) / 4, 256, 0, stream>>>(h1b, csr_src, rowptr, deg, dinv, b1, actb, N);

    // layer 2
    gemm2_mfma_kernel<<<512, 256, 0, stream>>>(actb, W2, h2b, N);
    agg2_lsm_kernel<<<(N + 3) / 4, 256, 0, stream>>>(h2b, csr_src, rowptr, deg, dinv, b2, (float*)d_out, N);
}